// Round 1
// baseline (437.452 us; speedup 1.0000x reference)
//
#include <hip/hip_runtime.h>
#include <stdint.h>

typedef unsigned short u16;
typedef __attribute__((ext_vector_type(8))) short bf16x8;
typedef __attribute__((ext_vector_type(4))) short s16x4;
typedef __attribute__((ext_vector_type(4))) float f32x4;

#define MFMA16(a,b,c) __builtin_amdgcn_mfma_f32_16x16x32_bf16((a),(b),(c),0,0,0)

__device__ __forceinline__ u16 f2bf(float f) {
  union { float f; uint32_t u; } v; v.f = f;
  return (u16)((v.u + 0x7fffu + ((v.u >> 16) & 1u)) >> 16);
}

// ---------- kernel 1: cast hidden_states fp32 -> bf16 ----------
__global__ void k_cast(const float* __restrict__ src, u16* __restrict__ dst, int n8) {
  int idx = blockIdx.x * 256 + threadIdx.x;
  if (idx >= n8) return;
  const float4* s = (const float4*)src + (size_t)idx * 2;
  float4 a = s[0], b = s[1];
  bf16x8 o;
  o[0] = (short)f2bf(a.x); o[1] = (short)f2bf(a.y);
  o[2] = (short)f2bf(a.z); o[3] = (short)f2bf(a.w);
  o[4] = (short)f2bf(b.x); o[5] = (short)f2bf(b.y);
  o[6] = (short)f2bf(b.z); o[7] = (short)f2bf(b.w);
  *(bf16x8*)(dst + (size_t)idx * 8) = o;
}

// ---------- kernel 2: transpose+cast a 1024x1024 weight: Wt[j][d] = bf16(W[d][j]) ----------
__global__ void k_wtrans(const float* __restrict__ W, u16* __restrict__ Wt) {
  __shared__ u16 tile[32][33];
  int bd = blockIdx.x >> 5, bj = blockIdx.x & 31;
  int tx = threadIdx.x & 31, ty = threadIdx.x >> 5;  // ty 0..7
#pragma unroll
  for (int i = 0; i < 32; i += 8)
    tile[ty + i][tx] = f2bf(W[(size_t)(bd * 32 + ty + i) * 1024 + bj * 32 + tx]);
  __syncthreads();
#pragma unroll
  for (int i = 0; i < 32; i += 8)
    Wt[(size_t)(bj * 32 + ty + i) * 1024 + bd * 32 + tx] = tile[tx][ty + i];
}

// ---------- kernel 3: zero output ----------
__global__ void k_zero(float4* __restrict__ p, int n4) {
  int idx = blockIdx.x * 256 + threadIdx.x;
  if (idx < n4) p[idx] = make_float4(0.f, 0.f, 0.f, 0.f);
}

// ---------- kernel 4: fused QKV GEMM (bf16 MFMA, 128x128 tile) ----------
// C[4096 x 3072] over K=1024. by selects which of Q/K/V (8 col-tiles each).
__global__ __launch_bounds__(256, 2) void k_qkv(
    const u16* __restrict__ hsb, const u16* __restrict__ Wt,
    const float* __restrict__ bq, const float* __restrict__ bk, const float* __restrict__ bv,
    u16* __restrict__ Qb, u16* __restrict__ Kb, u16* __restrict__ Vt) {
  __shared__ u16 a_lds[128][72];
  __shared__ u16 b_lds[128][72];
  const int tid = threadIdx.x;
  const int lane = tid & 63, wid = tid >> 6;
  const int l15 = lane & 15, quad = lane >> 4;
  const int wr = wid >> 1, wc = wid & 1;
  const int bx = blockIdx.x & 31;   // M tile
  const int by = blockIdx.x >> 5;   // 0..23
  const int Mbase = bx * 128;
  const int widx = by >> 3;               // 0=Q 1=K 2=V
  const int Nloc = (by & 7) * 128;        // col within the 1024-wide output

  f32x4 acc[4][4];
#pragma unroll
  for (int i = 0; i < 4; ++i)
#pragma unroll
    for (int j = 0; j < 4; ++j) acc[i][j] = (f32x4){0.f, 0.f, 0.f, 0.f};

  for (int kb = 0; kb < 16; ++kb) {
    const int kbase = kb * 64;
    __syncthreads();
#pragma unroll
    for (int i = 0; i < 4; ++i) {
      int ch = tid + i * 256;
      int r = ch >> 3, c = (ch & 7) * 8;
      *(bf16x8*)&a_lds[r][c] =
          *(const bf16x8*)(hsb + (size_t)(Mbase + r) * 1024 + kbase + c);
      *(bf16x8*)&b_lds[r][c] =
          *(const bf16x8*)(Wt + (size_t)widx * 1048576 + (size_t)(Nloc + r) * 1024 + kbase + c);
    }
    __syncthreads();
#pragma unroll
    for (int ks = 0; ks < 2; ++ks) {
      const int koff = ks * 32 + quad * 8;
      bf16x8 af[4], bfr[4];
#pragma unroll
      for (int mt = 0; mt < 4; ++mt) af[mt] = *(const bf16x8*)&a_lds[wr * 64 + mt * 16 + l15][koff];
#pragma unroll
      for (int nt = 0; nt < 4; ++nt) bfr[nt] = *(const bf16x8*)&b_lds[wc * 64 + nt * 16 + l15][koff];
#pragma unroll
      for (int mt = 0; mt < 4; ++mt)
#pragma unroll
        for (int nt = 0; nt < 4; ++nt)
          acc[mt][nt] = MFMA16(af[mt], bfr[nt], acc[mt][nt]);
    }
  }
  // epilogue: +bias, write bf16. Q/K natural [row][1024]; V transposed Vt[b][g][h][m].
  const float* bias = (widx == 0) ? bq : ((widx == 1) ? bk : bv);
#pragma unroll
  for (int nt = 0; nt < 4; ++nt) {
    const int jloc = Nloc + wc * 64 + nt * 16 + l15;
    const float bias_v = bias[jloc];
#pragma unroll
    for (int mt = 0; mt < 4; ++mt) {
      const int Mr0 = Mbase + wr * 64 + mt * 16 + quad * 4;
      if (widx == 2) {
        const int b = Mr0 >> 11, mseq = Mr0 & 2047;
        const int g = jloc >> 7, h = jloc & 127;
        s16x4 pk;
#pragma unroll
        for (int r = 0; r < 4; ++r) pk[r] = (short)f2bf(acc[mt][nt][r] + bias_v);
        *(s16x4*)(Vt + (((size_t)b * 8 + g) * 128 + h) * 2048 + mseq) = pk;
      } else {
        u16* dst = (widx == 0) ? Qb : Kb;
#pragma unroll
        for (int r = 0; r < 4; ++r)
          dst[(size_t)(Mr0 + r) * 1024 + jloc] = f2bf(acc[mt][nt][r] + bias_v);
      }
    }
  }
}

// ---------- kernel 5: grouped attention with softmax over g ----------
// grid 256 = 2 m-chunks x 2 batch x 64 n-tiles; 512 threads = 8 waves.
// Per m-iteration (128 m rows): each wave computes S^T[16m x 32n x 8g] (rows m),
// softmax over g in-register, P staged to LDS in 2 passes of 4 g; wave w does PV for g=w.
__global__ __launch_bounds__(512, 2) void k_attn(
    const u16* __restrict__ Qb, const u16* __restrict__ Kb,
    const u16* __restrict__ Vt, float* __restrict__ out) {
  __shared__ u16 p_lds[4][32][136];  // [g mod 4][n][m], stride 136 -> 2-way bank alias (free)
  const int tid = threadIdx.x;
  const int w = tid >> 6;
  const int lane = tid & 63;
  const int l15 = lane & 15, quad = lane >> 4;
  const int bx = blockIdx.x;
  const int ntile = bx & 63;
  const int bcoord = (bx >> 6) & 1;
  const int mc = bx >> 7;
  const int nbase = ntile * 32;
  const int g_own = w;

  f32x4 cacc[2][8];
#pragma unroll
  for (int i = 0; i < 2; ++i)
#pragma unroll
    for (int j = 0; j < 8; ++j) cacc[i][j] = (f32x4){0.f, 0.f, 0.f, 0.f};

  const size_t qrow0 = ((size_t)bcoord * 2048 + nbase) * 1024;

  for (int it = 0; it < 8; ++it) {
    const int mbase = mc * 1024 + it * 128;
    // ---- phase 1: scores S^T for this wave's 16 m-rows, all 32 n, all 8 g ----
    f32x4 sacc[8][2];
#pragma unroll
    for (int g = 0; g < 8; ++g)
#pragma unroll
      for (int nc = 0; nc < 2; ++nc) sacc[g][nc] = (f32x4){0.f, 0.f, 0.f, 0.f};

    const size_t krow = ((size_t)bcoord * 2048 + mbase + w * 16 + l15) * 1024;
#pragma unroll
    for (int g = 0; g < 8; ++g) {
#pragma unroll
      for (int ks = 0; ks < 4; ++ks) {
        const int hoff = g * 128 + ks * 32 + quad * 8;
        bf16x8 kf = *(const bf16x8*)(Kb + krow + hoff);
#pragma unroll
        for (int nc = 0; nc < 2; ++nc) {
          bf16x8 qf = *(const bf16x8*)(Qb + qrow0 + (size_t)(nc * 16 + l15) * 1024 + hoff);
          sacc[g][nc] = MFMA16(kf, qf, sacc[g][nc]);  // D[m][n] = K·Q^T
        }
      }
    }
    // ---- softmax over g (register-local: same lane/reg across the 8 g accs) ----
#pragma unroll
    for (int nc = 0; nc < 2; ++nc)
#pragma unroll
      for (int r = 0; r < 4; ++r) {
        float s[8];
#pragma unroll
        for (int g = 0; g < 8; ++g) s[g] = sacc[g][nc][r] * 0.03125f;  // /sqrt(1024)
        float mx = s[0];
#pragma unroll
        for (int g = 1; g < 8; ++g) mx = fmaxf(mx, s[g]);
        float sum = 0.f;
#pragma unroll
        for (int g = 0; g < 8; ++g) { s[g] = __expf(s[g] - mx); sum += s[g]; }
        const float rs = 1.0f / sum;
#pragma unroll
        for (int g = 0; g < 8; ++g) sacc[g][nc][r] = s[g] * rs;
      }
    // ---- phase 2: P -> LDS (2 passes of 4 g), then PV for owned g ----
#pragma unroll
    for (int pass = 0; pass < 2; ++pass) {
#pragma unroll
      for (int gg = 0; gg < 4; ++gg) {
        const int g = pass * 4 + gg;
#pragma unroll
        for (int nc = 0; nc < 2; ++nc) {
          s16x4 pk;
#pragma unroll
          for (int r = 0; r < 4; ++r) pk[r] = (short)f2bf(sacc[g][nc][r]);
          *(s16x4*)&p_lds[gg][nc * 16 + l15][w * 16 + quad * 4] = pk;
        }
      }
      __syncthreads();
      if ((g_own >> 2) == pass) {
        const int gg = g_own & 3;
        const size_t vbase = (((size_t)bcoord * 8 + g_own) * 128) * 2048;
#pragma unroll
        for (int ks = 0; ks < 4; ++ks) {
          bf16x8 pf0 = *(const bf16x8*)&p_lds[gg][l15][ks * 32 + quad * 8];
          bf16x8 pf1 = *(const bf16x8*)&p_lds[gg][16 + l15][ks * 32 + quad * 8];
#pragma unroll
          for (int hc = 0; hc < 8; ++hc) {
            bf16x8 vf = *(const bf16x8*)(Vt + vbase + (size_t)(hc * 16 + l15) * 2048 +
                                         mbase + ks * 32 + quad * 8);
            cacc[0][hc] = MFMA16(pf0, vf, cacc[0][hc]);
            cacc[1][hc] = MFMA16(pf1, vf, cacc[1][hc]);
          }
        }
      }
      __syncthreads();
    }
  }
  // ---- epilogue: atomic accumulate (m-chunks are disjoint partial sums) ----
#pragma unroll
  for (int nc = 0; nc < 2; ++nc)
#pragma unroll
    for (int hc = 0; hc < 8; ++hc)
#pragma unroll
      for (int r = 0; r < 4; ++r) {
        const int nrow = nbase + nc * 16 + quad * 4 + r;
        const size_t oidx =
            ((size_t)bcoord * 2048 + nrow) * 1024 + g_own * 128 + hc * 16 + l15;
        atomicAdd(out + oidx, cacc[nc][hc][r]);
      }
}

extern "C" void kernel_launch(void* const* d_in, const int* in_sizes, int n_in,
                              void* d_out, int out_size, void* d_ws, size_t ws_size,
                              hipStream_t stream) {
  const float* hs = (const float*)d_in[0];
  const float* Wq = (const float*)d_in[1];
  const float* bq = (const float*)d_in[2];
  const float* Wk = (const float*)d_in[3];
  const float* bk = (const float*)d_in[4];
  const float* Wv = (const float*)d_in[5];
  const float* bv = (const float*)d_in[6];
  float* out = (float*)d_out;

  u16* ws = (u16*)d_ws;
  u16* hsb = ws;                   // 4096x1024
  u16* Wt  = ws + 4194304;         // 3 x 1024x1024 (j-major)
  u16* Qb  = ws + 7340032;         // [b][n][1024]
  u16* Kb  = ws + 11534336;        // [b][m][1024]
  u16* Vt  = ws + 15728640;        // [b][g][h][m] = [2][8][128][2048]

  k_cast<<<2048, 256, 0, stream>>>(hs, hsb, 524288);
  k_wtrans<<<1024, 256, 0, stream>>>(Wq, Wt);
  k_wtrans<<<1024, 256, 0, stream>>>(Wk, Wt + 1048576);
  k_wtrans<<<1024, 256, 0, stream>>>(Wv, Wt + 2097152);
  k_qkv<<<32 * 24, 256, 0, stream>>>(hsb, Wt, bq, bk, bv, Qb, Kb, Vt);
  k_zero<<<4096, 256, 0, stream>>>((float4*)out, 1048576);
  k_attn<<<256, 512, 0, stream>>>(Qb, Kb, Vt, out);
}